// Round 4
// baseline (269.114 us; speedup 1.0000x reference)
//
#include <hip/hip_runtime.h>
#include <stdint.h>

// ---------------------------------------------------------------------------
// MS_SSA_Conv: spiking self-attention. T=4 B=8 C=384 N=1024 heads=8.
// R7 = R6 geometry (256x256 tile, BK=64, 8 waves, dbuf 128KB LDS, verified
//      0-conflict swizzle) + the m201 TWO-barrier phase structure:
//   per phase: {ds_read issue, stage issue} -> s_barrier -> lgkmcnt(0)
//              -> sched_barrier(0) [rule #18] -> setprio(1) 16xMFMA -> s_barrier
//   The pre-MFMA barrier aligns waves so ds_reads of other waves are in
//   flight WHILE this wave runs MFMA (LDS pipe || matrix pipe across waves).
//   R6 had only the post-MFMA barrier -> lockstep -> pipes serialized
//   (measured 6800 cyc/K-tile vs ~2600 component sum).
// ---------------------------------------------------------------------------

typedef unsigned short u16;
typedef __attribute__((ext_vector_type(8))) short short8v;
typedef __attribute__((ext_vector_type(4))) float f32x4;

#define AS1 __attribute__((address_space(1)))
#define AS3 __attribute__((address_space(3)))

__device__ __forceinline__ void async16(const void* g, void* l) {
    __builtin_amdgcn_global_load_lds((const AS1 unsigned int*)g,
                                     (AS3 unsigned int*)l, 16, 0, 0);
}
__device__ __forceinline__ f32x4 mfma_bf16(short8v a, short8v b, f32x4 c) {
    return __builtin_amdgcn_mfma_f32_16x16x32_bf16(a, b, c, 0, 0, 0);
}
__device__ __forceinline__ f32x4 mfma_f16(short8v a, short8v b, f32x4 c) {
    return __builtin_amdgcn_mfma_f32_16x16x32_f16(a, b, c, 0, 0, 0);
}

__device__ __forceinline__ u16 f2bf(float f) {  // RNE fp32->bf16
    uint32_t x = __float_as_uint(f);
    return (u16)((x + 0x7FFFu + ((x >> 16) & 1u)) >> 16);
}

#define SPIKE_H ((u16)0x3C00)  // fp16 1.0 (xs)
#define SPIKE_B ((u16)0x3F80)  // bf16 1.0 (q/k/v spikes, kvs mask)

// ---------------------------------------------------------------------------
// K0: weights. Ah [1280][768] fp16 2-part split (rows 1152.. zero-padded);
// Aproj [384][384] bf16.
// ---------------------------------------------------------------------------
__global__ void prep_kernel(const float* __restrict__ qw, const float* __restrict__ kw,
                            const float* __restrict__ vw, const float* __restrict__ pw,
                            u16* __restrict__ Ah, u16* __restrict__ Aproj) {
    int id = blockIdx.x * 256 + threadIdx.x;
    if (id >= 1280 * 384) return;
    int m = id / 384, c = id % 384;
    u16* row = Ah + (size_t)m * 768;
    if (m >= 1152) { row[c] = 0; row[384 + c] = 0; return; }
    int br = m / 384, o = m % 384;
    const float* W = (br == 0) ? qw : (br == 1) ? kw : vw;
    float w = W[o * 384 + c];
    union H { _Float16 h; u16 u; } u0, u1;
    u0.h = (_Float16)w;
    float r1 = w - (float)u0.h;
    u1.h = (_Float16)r1;
    row[c] = u0.u;
    row[384 + c] = u1.u;
    if (br == 0) Aproj[o * 384 + c] = f2bf(pw[o * 384 + c]);
}

// ---------------------------------------------------------------------------
// K1: shortcut LIF on x -> xs[t,b,n,c] fp16 spikes.
// ---------------------------------------------------------------------------
__global__ __launch_bounds__(256) void lifx_kernel(const float* __restrict__ x,
                                                   u16* __restrict__ xs) {
    __shared__ u16 Tr[64 * 72];
    int b = blockIdx.z, c0 = blockIdx.y * 64, n0 = blockIdx.x * 64;
    int tid = threadIdx.x;
    int nj = (tid & 15) * 4;
    int ci = tid >> 4;
    float v[4][4];
#pragma unroll
    for (int p = 0; p < 4; p++)
#pragma unroll
        for (int e = 0; e < 4; e++) v[p][e] = 0.0f;

    for (int t = 0; t < 4; t++) {
#pragma unroll
        for (int p = 0; p < 4; p++) {
            const float* src = x + ((size_t)((t * 8 + b) * 384 + c0 + p * 16 + ci)) * 1024 + n0 + nj;
            float4 xv = *(const float4*)src;
            float xa[4] = {xv.x, xv.y, xv.z, xv.w};
#pragma unroll
            for (int e = 0; e < 4; e++) {
                float vv = v[p][e];
                vv = __fadd_rn(vv, __fmul_rn(__fsub_rn(xa[e], vv), 0.5f));
                bool sp = (vv >= 0.5f);
                v[p][e] = sp ? 0.0f : vv;
                Tr[(nj + e) * 72 + p * 16 + ci] = sp ? SPIKE_H : (u16)0;
            }
        }
        __syncthreads();
#pragma unroll
        for (int p = 0; p < 4; p++) {
            int nr = p * 16 + (tid >> 4);
            int c4 = (tid & 15) * 4;
            *(ushort4*)(xs + ((size_t)((t * 8 + b) * 1024 + n0 + nr)) * 384 + c0 + c4) =
                *(const ushort4*)&Tr[nr * 72 + c4];
        }
        __syncthreads();
    }
}

// ---------------------------------------------------------------------------
// K2: QKV conv (2-part fp16, K=768) + BN + LIF over t (from acc, epilogue).
// Tile 256 o x 256 col (col = wn4*64 + t*16 + l15 -> 4t x 64n), BK=64,
// 12 K-tiles x 4 phases x 2 barriers. 8 waves: wmh = wave>>2, wn4 = wave&3.
// grid (nt=16, mt=5, b=8), 512 threads.
// ---------------------------------------------------------------------------
__global__ __launch_bounds__(512, 2) void qkv_kernel(
    const u16* __restrict__ Ah, const u16* __restrict__ xs, u16* __restrict__ qs,
    const float* __restrict__ qg, const float* __restrict__ qb, const float* __restrict__ qm, const float* __restrict__ qv,
    const float* __restrict__ kg, const float* __restrict__ kb, const float* __restrict__ km, const float* __restrict__ kvr,
    const float* __restrict__ vg, const float* __restrict__ vb, const float* __restrict__ vm, const float* __restrict__ vvr) {
    __shared__ __align__(16) u16 At[2][2][8192];  // [buf][rowhalf][128*64]
    __shared__ __align__(16) u16 Bt[2][2][8192];  // [buf][colhalf][128*64]
    __shared__ float bnS[256], bnM[256], bnB[256];
    __shared__ int roff[256];

    const int b = blockIdx.z, mt = blockIdx.y, nt = blockIdx.x;
    const int m0 = mt * 256, n0 = nt * 64;
    const int tid = threadIdx.x, wave = tid >> 6, lane = tid & 63;
    const int l15 = lane & 15, quad = lane >> 4;
    const int wmh = wave >> 2;        // 0/1: row half (128 rows)
    const int wn4 = wave & 3;         // 0..3: 64-col group
    const int bh = wn4 >> 1;          // B half
    const int cb = (wn4 & 1) * 64;    // col base within B half

    // per-row BN params + dst offset table (branch folded into offset:
    // qs/ks/vs are contiguous, 12582912 u16 apart)
    if (tid < 256) {
        int g = m0 + tid;
        if (g < 1152) {
            int br = g / 384, o = g - br * 384;
            const float* gp = (br == 0) ? qg : (br == 1) ? kg : vg;
            const float* bp = (br == 0) ? qb : (br == 1) ? kb : vb;
            const float* mp = (br == 0) ? qm : (br == 1) ? km : vm;
            const float* vp = (br == 0) ? qv : (br == 1) ? kvr : vvr;
            bnS[tid] = gp[o] / sqrtf(vp[o] + 1e-5f);
            bnM[tid] = mp[o];
            bnB[tid] = bp[o];
            roff[tid] = br * 12582912 + o;
        } else {
            bnS[tid] = 0.f; bnM[tid] = 0.f; bnB[tid] = 0.f; roff[tid] = 0;
        }
    }

    // staging geometry: load l = d*512 + tid covers (row/col = d*64 + (tid>>3),
    // chunk = tid&7), source chunk pre-swizzled (involution with read side)
    const int cl = tid >> 3;                       // 0..63
    const int cs8 = ((tid & 7) ^ (cl & 7)) * 8;    // swizzled chunk (u16)
    const int dst0 = tid * 8;                      // linear LDS dest (u16)

    const u16* pA = Ah + (size_t)(m0 + cl) * 768 + cs8;
    auto mkB = [&](int C) {  // tile col C -> xs address (t,n interleave)
        int t = (C >> 4) & 3;
        int nl = (C >> 6) * 16 + (C & 15);
        return xs + ((size_t)((t * 8 + b) * 1024 + n0 + nl)) * 384 + cs8;
    };
    const u16* pB00 = mkB(cl);        // B half 0, ld 0
    const u16* pB01 = mkB(64 + cl);   // B half 0, ld 1
    const u16* pB10 = mkB(128 + cl);  // B half 1, ld 0
    const u16* pB11 = mkB(192 + cl);  // B half 1, ld 1

    auto stA0 = [&](int Tn) { int buf = Tn & 1, kk = Tn * 64;
        async16(pA + kk,          &At[buf][0][dst0]);
        async16(pA + 49152 + kk,  &At[buf][0][4096 + dst0]); };
    auto stA1 = [&](int Tn) { int buf = Tn & 1, kk = Tn * 64;
        async16(pA + 98304 + kk,          &At[buf][1][dst0]);
        async16(pA + 98304 + 49152 + kk,  &At[buf][1][4096 + dst0]); };
    auto stB0 = [&](int Tn) { int buf = Tn & 1, kk = Tn * 64;
        int ck = (kk >= 384) ? kk - 384 : kk;  // 2-part split: B repeats
        async16(pB00 + ck, &Bt[buf][0][dst0]);
        async16(pB01 + ck, &Bt[buf][0][4096 + dst0]); };
    auto stB1 = [&](int Tn) { int buf = Tn & 1, kk = Tn * 64;
        int ck = (kk >= 384) ? kk - 384 : kk;
        async16(pB10 + ck, &Bt[buf][1][dst0]);
        async16(pB11 + ck, &Bt[buf][1][4096 + dst0]); };

    // fragment read constants (swizzled chunk: (k-group)^(row&7), row&7==l15&7)
    const int ch0 = (quad ^ (l15 & 7)) * 8;        // kk2 = 0
    const int ch1 = ((4 + quad) ^ (l15 & 7)) * 8;  // kk2 = 1
    const int abase = l15 * 64;

    f32x4 acc[8][4];
#pragma unroll
    for (int i = 0; i < 8; i++)
#pragma unroll
        for (int j = 0; j < 4; j++) acc[i][j] = (f32x4){0.f, 0.f, 0.f, 0.f};

    short8v af[4], bf[4];

#define LOAD_A(BUF, QH, CH) { const u16* Ap = &At[BUF][wmh][(QH)*4096 + abase + (CH)]; \
    af[0] = *(const short8v*)Ap;          af[1] = *(const short8v*)(Ap + 1024); \
    af[2] = *(const short8v*)(Ap + 2048); af[3] = *(const short8v*)(Ap + 3072); }
#define LOAD_B(BUF, CH) { const u16* Bp = &Bt[BUF][bh][cb*64 + abase + (CH)]; \
    bf[0] = *(const short8v*)Bp;          bf[1] = *(const short8v*)(Bp + 1024); \
    bf[2] = *(const short8v*)(Bp + 2048); bf[3] = *(const short8v*)(Bp + 3072); }
#define MFMA16(QH) { __builtin_amdgcn_s_setprio(1); \
    _Pragma("unroll") for (int i = 0; i < 4; i++) \
    _Pragma("unroll") for (int j = 0; j < 4; j++) \
        acc[(QH)*4 + i][j] = mfma_f16(af[i], bf[j], acc[(QH)*4 + i][j]); \
    __builtin_amdgcn_s_setprio(0); }
// m201 phase tail: align waves (reads ISSUED by all), then each wave waits
// its own ds_reads; sched_barrier stops MFMA hoisting above (rule #18).
#define PHASE_SYNC { asm volatile("s_barrier\n\ts_waitcnt lgkmcnt(0)" ::: "memory"); \
    __builtin_amdgcn_sched_barrier(0); }

    // prologue: stage tile 0, full drain once
    stA0(0); stB0(0); stA1(0); stB1(0);
    __syncthreads();

#pragma unroll 1
    for (int T = 0; T < 12; T++) {
        int buf = T & 1;
        bool pf = (T < 11);
        // q0: (rowhalf 0, k-half 0); stage A0+B0 of T+1
        LOAD_A(buf, 0, ch0)
        LOAD_B(buf, ch0)
        if (pf) { stA0(T + 1); stB0(T + 1); }
        PHASE_SYNC
        MFMA16(0)
        asm volatile("s_barrier" ::: "memory");
        // q1: (rowhalf 1, k-half 0) -- reuse bf; stage A1+B1 of T+1
        LOAD_A(buf, 1, ch0)
        if (pf) { stA1(T + 1); stB1(T + 1); }
        PHASE_SYNC
        MFMA16(1)
        asm volatile("s_barrier" ::: "memory");
        // q2: (rowhalf 0, k-half 1)
        LOAD_A(buf, 0, ch1)
        LOAD_B(buf, ch1)
        PHASE_SYNC
        MFMA16(0)
        asm volatile("s_barrier" ::: "memory");
        // q3: (rowhalf 1, k-half 1); drain (issued >=2 phases ago) + publish
        LOAD_A(buf, 1, ch1)
        PHASE_SYNC
        MFMA16(1)
        asm volatile("s_waitcnt vmcnt(0)\n\ts_barrier" ::: "memory");
    }
#undef LOAD_A
#undef LOAD_B
#undef MFMA16
#undef PHASE_SYNC

    // epilogue: BN + LIF over t (exact numpy order) from accumulators
    const int nn = n0 + wn4 * 16 + l15;
#pragma unroll
    for (int mi = 0; mi < 8; mi++) {
        int rbw = wmh * 128 + (mi >> 2) * 64 + (mi & 3) * 16;  // wave-uniform
        if (m0 + rbw >= 1152) continue;                        // padded rows
        int rbase = rbw + quad * 4;
        float4 s4 = *(const float4*)&bnS[rbase];
        float4 m4 = *(const float4*)&bnM[rbase];
        float4 b4 = *(const float4*)&bnB[rbase];
        float sc[4] = {s4.x, s4.y, s4.z, s4.w};
        float mn[4] = {m4.x, m4.y, m4.z, m4.w};
        float bt[4] = {b4.x, b4.y, b4.z, b4.w};
        int ro = roff[rbase];
        u16 sv[4][4];  // [t][e]
#pragma unroll
        for (int e = 0; e < 4; e++) {
            float vv = 0.0f;
#pragma unroll
            for (int t = 0; t < 4; t++) {
                float a = acc[mi][t][e];
                a = __fadd_rn(__fmul_rn(__fsub_rn(a, mn[e]), sc[e]), bt[e]);
                vv = __fadd_rn(vv, __fmul_rn(__fsub_rn(a, vv), 0.5f));
                bool sp = (vv >= 0.5f);
                vv = sp ? 0.0f : vv;
                sv[t][e] = sp ? SPIKE_B : (u16)0;
            }
        }
#pragma unroll
        for (int t = 0; t < 4; t++) {
            ushort4 o4;
            o4.x = sv[t][0]; o4.y = sv[t][1]; o4.z = sv[t][2]; o4.w = sv[t][3];
            *(ushort4*)(qs + (size_t)ro + ((size_t)((t * 8 + b) * 1024 + nn)) * 384) = o4;
        }
    }
}

// ---------------------------------------------------------------------------
// K3: kv[t,b,c] = sum_n k*v. 16B loads, 8 ch/thread, LDS pre-reduce.
// grid (nc=16, tb=32), 384 thr: tid = rr*48 + c8.
// ---------------------------------------------------------------------------
__global__ void kvred_kernel(const u16* __restrict__ ks, const u16* __restrict__ vs,
                             float* __restrict__ r) {
    __shared__ float red[384];
    int tb = blockIdx.y, nc = blockIdx.x;
    int tid = threadIdx.x;
    int rr = tid / 48, c8 = tid % 48;
    red[tid] = 0.0f;
    __syncthreads();

    float cnt[8];
#pragma unroll
    for (int e = 0; e < 8; e++) cnt[e] = 0.0f;

    size_t base = ((size_t)(tb * 1024 + nc * 64 + rr)) * 384 + c8 * 8;
#pragma unroll 2
    for (int it = 0; it < 8; it++) {
        size_t off = base + (size_t)it * 8 * 384;
        uint4 ka = *(const uint4*)(ks + off);
        uint4 va = *(const uint4*)(vs + off);
        uint32_t w0 = ka.x & va.x, w1 = ka.y & va.y, w2 = ka.z & va.z, w3 = ka.w & va.w;
        const uint32_t S = SPIKE_B;
        if ((w0 & 0xFFFFu) == S) cnt[0] += 1.0f;
        if ((w0 >> 16) == S)     cnt[1] += 1.0f;
        if ((w1 & 0xFFFFu) == S) cnt[2] += 1.0f;
        if ((w1 >> 16) == S)     cnt[3] += 1.0f;
        if ((w2 & 0xFFFFu) == S) cnt[4] += 1.0f;
        if ((w2 >> 16) == S)     cnt[5] += 1.0f;
        if ((w3 & 0xFFFFu) == S) cnt[6] += 1.0f;
        if ((w3 >> 16) == S)     cnt[7] += 1.0f;
    }
#pragma unroll
    for (int e = 0; e < 8; e++) atomicAdd(&red[c8 * 8 + e], cnt[e]);
    __syncthreads();
    atomicAdd(&r[tb * 384 + tid], red[tid]);
}

// K4: talking heads (8x8 fp32) + LIF over t -> kvs[t,b,c] bf16 {0,1} mask
__global__ void talking_kernel(const float* __restrict__ r, const float* __restrict__ th,
                               u16* __restrict__ kvs) {
    int id = blockIdx.x * 256 + threadIdx.x;
    if (id >= 8 * 384) return;
    int b = id / 384, c = id % 384;
    int oh = c / 48, d = c % 48;
    float v = 0.0f;
    for (int t = 0; t < 4; t++) {
        const float* rr = r + (t * 8 + b) * 384 + d;
        float s = 0.0f;
#pragma unroll
        for (int h = 0; h < 8; h++) s = __fmaf_rn(th[oh * 8 + h], rr[h * 48], s);
        v = __fadd_rn(v, __fmul_rn(__fsub_rn(s, v), 0.5f));
        bool sp = (v >= 0.5f);
        v = sp ? 0.0f : v;
        kvs[(t * 8 + b) * 384 + c] = sp ? SPIKE_B : (u16)0;
    }
}

// ---------------------------------------------------------------------------
// K5: proj conv (K=384 bf16) + fused kvs gate + bias + BN + residual.
// 128x128 tiles, dbuf LDS, counted-vmcnt pipeline. grid (nt=8, mt=3, tb=32).
// ---------------------------------------------------------------------------
__global__ __launch_bounds__(256, 2) void proj_kernel(
    const u16* __restrict__ Aproj, const u16* __restrict__ qs, const u16* __restrict__ kvs,
    const float* __restrict__ xin,
    const float* __restrict__ pb, const float* __restrict__ pg, const float* __restrict__ pbe,
    const float* __restrict__ pm, const float* __restrict__ pv, float* __restrict__ out) {
    __shared__ __align__(16) u16 At[2][8192];
    __shared__ __align__(16) u16 Bt[2][8192];

    int tb = blockIdx.z, mt = blockIdx.y, nt = blockIdx.x;
    int m0 = mt * 128, n0 = nt * 128;
    int tid = threadIdx.x, wave = tid >> 6, lane = tid & 63;
    int l15 = lane & 15, quad = lane >> 4;
    int wm = (wave & 1) * 64, wn = (wave >> 1) * 64;

    const u16* Bsrc = qs + ((size_t)(tb * 1024 + n0)) * 384;
    const u16* mbase = kvs + tb * 384;

    auto stage = [&](int s) {
        int kk = s * 64;
        int buf = s & 1;
#pragma unroll
        for (int ii = 0; ii < 4; ii++) {
            int l = ii * 256 + tid;
            int row = l >> 3;
            int cs = (l & 7) ^ (row & 7);
            async16(Aproj + (size_t)(m0 + row) * 384 + kk + cs * 8, &At[buf][l * 8]);
            async16(Bsrc + (size_t)row * 384 + kk + cs * 8, &Bt[buf][l * 8]);
        }
    };

    f32x4 acc[4][4];
#pragma unroll
    for (int i = 0; i < 4; i++)
#pragma unroll
        for (int j = 0; j < 4; j++) acc[i][j] = (f32x4){0.f, 0.f, 0.f, 0.f};

    stage(0);
    stage(1);

#pragma unroll 1
    for (int kkb = 0; kkb < 6; kkb++) {
        int buf = kkb & 1;
        int kk = kkb * 64;
        if (kkb < 5) asm volatile("s_waitcnt vmcnt(8)\n\ts_barrier" ::: "memory");
        else         asm volatile("s_waitcnt vmcnt(0)\n\ts_barrier" ::: "memory");

#pragma unroll
        for (int h = 0; h < 2; h++) {
            int g = h * 4 + quad;
            short8v msk = *(const short8v*)(mbase + kk + g * 8);
            short8v af[4], bfr[4];
#pragma unroll
            for (int i = 0; i < 4; i++) {
                int row = wm + i * 16 + l15;
                int ch = g ^ (row & 7);
                af[i] = *(const short8v*)&At[buf][row * 64 + ch * 8];
            }
#pragma unroll
            for (int j = 0; j < 4; j++) {
                int nr = wn + j * 16 + l15;
                int ch = g ^ (nr & 7);
                bfr[j] = *(const short8v*)&Bt[buf][nr * 64 + ch * 8] & msk;  // gate
            }
            __builtin_amdgcn_s_setprio(1);
#pragma unroll
            for (int i = 0; i < 4; i++)
#pragma unroll
                for (int j = 0; j < 4; j++) acc[i][j] = mfma_bf16(af[i], bfr[j], acc[i][j]);
            __builtin_amdgcn_s_setprio(0);
        }

        asm volatile("s_waitcnt lgkmcnt(0)\n\ts_barrier" ::: "memory");
        if (kkb + 2 < 6) stage(kkb + 2);
    }

    // epilogue: y = conv+bias; (y-mean)*scale+beta; + identity (numpy order)
#pragma unroll
    for (int i = 0; i < 4; i++) {
#pragma unroll
        for (int e = 0; e < 4; e++) {
            int o = m0 + wm + i * 16 + quad * 4 + e;
            float scale = pg[o] / sqrtf(pv[o] + 1e-5f);
            float mean = pm[o], beta = pbe[o], bias = pb[o];
#pragma unroll
            for (int j = 0; j < 4; j++) {
                int n = n0 + wn + j * 16 + l15;
                size_t idx = ((size_t)tb * 384 + o) * 1024 + n;
                float y = __fadd_rn(acc[i][j][e], bias);
                y = __fadd_rn(__fmul_rn(__fsub_rn(y, mean), scale), beta);
                out[idx] = __fadd_rn(y, xin[idx]);
            }
        }
    }
}

// ---------------------------------------------------------------------------
extern "C" void kernel_launch(void* const* d_in, const int* in_sizes, int n_in,
                              void* d_out, int out_size, void* d_ws, size_t ws_size,
                              hipStream_t stream) {
    (void)in_sizes; (void)n_in; (void)out_size; (void)ws_size;
    const float* x  = (const float*)d_in[0];
    const float* qw = (const float*)d_in[1];
    const float* kw = (const float*)d_in[2];
    const float* vw = (const float*)d_in[3];
    const float* th = (const float*)d_in[4];
    const float* pw = (const float*)d_in[5];
    const float* pb = (const float*)d_in[6];
    const float* qg = (const float*)d_in[7],  *qbe = (const float*)d_in[8];
    const float* qm = (const float*)d_in[9],  *qv  = (const float*)d_in[10];
    const float* kg = (const float*)d_in[11], *kbe = (const float*)d_in[12];
    const float* km = (const float*)d_in[13], *kv_ = (const float*)d_in[14];
    const float* vg = (const float*)d_in[15], *vbe = (const float*)d_in[16];
    const float* vm = (const float*)d_in[17], *vv_ = (const float*)d_in[18];
    const float* pg = (const float*)d_in[19], *pbe = (const float*)d_in[20];
    const float* pm = (const float*)d_in[21], *pv  = (const float*)d_in[22];
    float* out = (float*)d_out;

    char* w = (char*)d_ws;
    const size_t SPIKES = (size_t)32 * 1024 * 384 * 2;  // 25,165,824 B each
    u16* xs    = (u16*)(w);
    u16* qs    = (u16*)(w + SPIKES);
    u16* ks    = (u16*)(w + 2 * SPIKES);
    u16* vs    = (u16*)(w + 3 * SPIKES);
    u16* Ah    = (u16*)(w + 4 * SPIKES);                         // 1,966,080 B
    u16* Aproj = (u16*)(w + 4 * SPIKES + 1966080);               //   294,912 B
    float* r   = (float*)(w + 4 * SPIKES + 1966080 + 294912);    //    49,152 B
    u16* kvs   = (u16*)(w + 4 * SPIKES + 1966080 + 294912 + 49152);  // 24,576 B

    hipMemsetAsync(r, 0, 32 * 384 * sizeof(float), stream);

    prep_kernel<<<1920, 256, 0, stream>>>(qw, kw, vw, pw, Ah, Aproj);
    lifx_kernel<<<dim3(16, 6, 8), 256, 0, stream>>>(x, xs);
    qkv_kernel<<<dim3(16, 5, 8), 512, 0, stream>>>(Ah, xs, qs,
                                                   qg, qbe, qm, qv,
                                                   kg, kbe, km, kv_,
                                                   vg, vbe, vm, vv_);
    kvred_kernel<<<dim3(16, 32), 384, 0, stream>>>(ks, vs, r);
    talking_kernel<<<12, 256, 0, stream>>>(r, th, kvs);
    proj_kernel<<<dim3(8, 3, 32), 256, 0, stream>>>(Aproj, qs, kvs, x, pb, pg, pbe, pm, pv, out);
}